// Round 12
// baseline (33.302 us; speedup 1.0000x reference)
//
#include <hip/hip_runtime.h>
#include <hip/hip_bf16.h>

#define NATOM 4096
#define NH 8
#define DIMD 64
#define BLK 128
#define NROW 32
#define BPS 4
#define ROWSTRIDE (NH * DIMD)   // 512 floats
#define SCALE 0.125f
#define L2E 1.4426950408889634f

#define V_LD 136    // prep transpose scratch only
#define P_LD 136    // fallback only
#define K_LDF 72    // fallback only

#define HEAD_ELEMS (NATOM * DIMD)               // 262144 bf16 per head plane
#define WS_NEEDED  (2u * NH * HEAD_ELEMS * 2u)  // Kb + Vt, bf16

typedef __attribute__((ext_vector_type(8))) short bf16x8;
typedef __attribute__((ext_vector_type(4))) float f32x4;
typedef __attribute__((ext_vector_type(16))) float f32x16;
typedef __attribute__((ext_vector_type(4))) unsigned int u32x4;

__device__ __forceinline__ short f2bf(float x) {
    unsigned int u = __builtin_bit_cast(unsigned int, x);
    unsigned int r = (u + 0x7fffu + ((u >> 16) & 1u)) >> 16;
    return (short)r;
}
__device__ __forceinline__ unsigned int cvtpk(float lo, float hi) {
    unsigned int r;
    asm("v_cvt_pk_bf16_f32 %0, %1, %2" : "=v"(r) : "v"(lo), "v"(hi));
    return r;
}

// ---------------- prep kernel: 512 blocks, h-major XCD swizzle ----------------
// Kb: bf16 [h][n][d] (natural).  Vt: bf16 [h][d][perm(n)] where within each
// 16-key group, column c = kb16*16 + hi*8 + j holds key
// kb16*16 + (j&3) + 8*(j>>2) + 4*hi  -- makes PV's 32x32 B-fragment equal
// acc regs 0..7 / 8..15 of the QK^T S-tile (P never leaves registers).
extern "C" __global__ __launch_bounds__(256)
void prep_kernel(const float* __restrict__ k, const float* __restrict__ v,
                 short* __restrict__ Kb, short* __restrict__ Vt)
{
    __shared__ short Tr[DIMD * V_LD];
    const int bid  = blockIdx.x;
    const int h    = bid & 7;
    const int part = bid >> 3;          // 0..63
    const int t    = threadIdx.x;

    if (part < 32) {
        const int nb = part;
        #pragma unroll
        for (int i = 0; i < 4; ++i) {
            int idx = i * 256 + t;
            int row = idx >> 3;
            int d0  = (idx & 7) * 8;
            const float* src = k + (size_t)(nb * BLK + row) * ROWSTRIDE + h * DIMD + d0;
            float4 a = *(const float4*)src;
            float4 c = *(const float4*)(src + 4);
            bf16x8 f;
            f[0] = f2bf(a.x); f[1] = f2bf(a.y); f[2] = f2bf(a.z); f[3] = f2bf(a.w);
            f[4] = f2bf(c.x); f[5] = f2bf(c.y); f[6] = f2bf(c.z); f[7] = f2bf(c.w);
            *(bf16x8*)(Kb + (size_t)h * HEAD_ELEMS + (size_t)(nb * BLK + row) * DIMD + d0) = f;
        }
    } else {
        const int nb = part - 32;
        const int vd = t & 63;
        const int g  = t >> 6;
        const float* vp = v + (size_t)(nb * BLK) * ROWSTRIDE + h * DIMD + vd;
        #pragma unroll
        for (int i = 0; i < 8; ++i) {
            int n4 = i * 16 + g * 4;
            const float* vr = vp + (size_t)n4 * ROWSTRIDE;
            short4 s4;
            s4.x = f2bf(vr[0 * ROWSTRIDE]);
            s4.y = f2bf(vr[1 * ROWSTRIDE]);
            s4.z = f2bf(vr[2 * ROWSTRIDE]);
            s4.w = f2bf(vr[3 * ROWSTRIDE]);
            *(short4*)&Tr[vd * V_LD + n4] = s4;   // Tr column = natural local key
        }
        __syncthreads();
        #pragma unroll
        for (int i = 0; i < 4; ++i) {
            int s  = i * 256 + t;
            int d  = s >> 4;
            int cc = s & 15;                       // 8-col group
            int c8 = cc * 8;
            int kA = (cc >> 1) * 16 + (cc & 1) * 4;
            short4 a  = *(const short4*)&Tr[d * V_LD + kA];
            short4 c4 = *(const short4*)&Tr[d * V_LD + kA + 8];
            bf16x8 f;
            f[0] = a.x;  f[1] = a.y;  f[2] = a.z;  f[3] = a.w;
            f[4] = c4.x; f[5] = c4.y; f[6] = c4.z; f[7] = c4.w;
            *(bf16x8*)(Vt + (size_t)h * HEAD_ELEMS + (size_t)d * NATOM + nb * BLK + c8) = f;
        }
    }
}

// ---------------- main kernel: 32x32 MFMA flash attn, 2 waves/block, 2 blocks/CU ----------------
// Grid 512 x 128thr: h = bid&7 (XCD-local), br = bid>>3 = 64-query block, rb = br>>1.
// Two independent blocks per CU -> cross-block latency hiding; per-CU LDS read
// traffic stays at the 32x32-halved level (128 b128/iter).
// S^T = mfma_32x32x16(K, Q): lane holds S[key = mt*32 + (reg&3)+8*(reg>>2)+4hi][q = lane&31]
// P stays in registers: pf[kb16] = cvtpk of sA[kb16>>1] regs (kb16&1)*8 .. +8
// O^T = mfma_32x32x16(Vt, P): lane holds O[q][d = dmt*32 + (reg&3)+8*(reg>>2)+4hi]
// Unnormalized exp2 (log2 domain, SCALE*L2E in Q); denominator = per-lane f32
// sum + ONE shfl_xor(32) in the epilogue.
// LDS: K [128][64], V [64][128], XOR chunk swizzle (chunk ^= row&7) both sides.
extern "C" __global__ __launch_bounds__(128)
void bsattn_main(const float* __restrict__ q,
                 const short* __restrict__ Kb,
                 const short* __restrict__ Vt,
                 float* __restrict__ out)
{
    __shared__ short Ksh[2][BLK * DIMD];      // 32 KB
    __shared__ short Vsh[2][DIMD * BLK];      // 32 KB

    const int bid = blockIdx.x;
    const int h   = bid & 7;
    const int br  = bid >> 3;          // 64-query block, 0..63
    const int rb  = br >> 1;           // 128-row band block
    const int t   = threadIdx.x;
    const int w   = t >> 6;            // wave 0..1
    const int lane = t & 63;
    const int lc  = lane & 31;
    const int hi  = lane >> 5;

    // ---- Q fragments (SCALE*L2E folded): q = lane&31, d = kc*16 + hi*8 + j ----
    const int qrow = br * 64 + w * 32 + lc;
    const float* qp = q + (size_t)qrow * ROWSTRIDE + h * DIMD;
    bf16x8 qf[4];
    #pragma unroll
    for (int kc = 0; kc < 4; ++kc) {
        const float* p = qp + kc * 16 + hi * 8;
        float4 a = *(const float4*)p;
        float4 b = *(const float4*)(p + 4);
        bf16x8 f;
        f[0] = f2bf(a.x * (SCALE * L2E)); f[1] = f2bf(a.y * (SCALE * L2E));
        f[2] = f2bf(a.z * (SCALE * L2E)); f[3] = f2bf(a.w * (SCALE * L2E));
        f[4] = f2bf(b.x * (SCALE * L2E)); f[5] = f2bf(b.y * (SCALE * L2E));
        f[6] = f2bf(b.z * (SCALE * L2E)); f[7] = f2bf(b.w * (SCALE * L2E));
        qf[kc] = f;
    }

    const short* kbase = Kb + (size_t)h * HEAD_ELEMS;
    const short* vbase = Vt + (size_t)h * HEAD_ELEMS;

    f32x16 oacc[2] = {};
    float sv = 0.0f;

    const int kb0 = (rb - BPS > 0) ? (rb - BPS) : 0;
    const int kb1 = (rb + BPS < NROW - 1) ? (rb + BPS) : (NROW - 1);

    const short* kgp = kbase + (size_t)kb0 * BLK * DIMD;
    const short* vgp = vbase + (size_t)kb0 * BLK;
    bf16x8 kpre[8], vpre[8];

#define LOADREGS()                                                               \
    {                                                                            \
        _Pragma("unroll")                                                        \
        for (int i = 0; i < 8; ++i) {                                            \
            int idx = i * 128 + t;                                               \
            kpre[i] = *(const bf16x8*)(kgp + (size_t)(idx >> 3) * DIMD + (idx & 7) * 8);   \
            vpre[i] = *(const bf16x8*)(vgp + (size_t)(idx >> 4) * NATOM + (idx & 15) * 8); \
        }                                                                        \
        kgp += BLK * DIMD; vgp += BLK;                                           \
    }

#define STAGE(buf)                                                               \
    {                                                                            \
        _Pragma("unroll")                                                        \
        for (int i = 0; i < 8; ++i) {                                            \
            int idx = i * 128 + t;                                               \
            int kr = idx >> 3, kch = idx & 7;                                    \
            *(bf16x8*)&Ksh[buf][kr * DIMD + ((kch ^ (kr & 7)) << 3)] = kpre[i];  \
            int vd = idx >> 4, vch = idx & 15;                                   \
            *(bf16x8*)&Vsh[buf][vd * BLK + ((vch ^ (vd & 7)) << 3)] = vpre[i];   \
        }                                                                        \
    }

    LOADREGS();
    STAGE(0);
    if (kb0 < kb1) LOADREGS();
    __syncthreads();

    int cur = 0;
    for (int kb = kb0; kb <= kb1; ++kb) {
        const short* ks = &Ksh[cur][0];
        const short* vs = &Vsh[cur][0];

        // ---- S^T tiles: 4 x (32 keys x 32 q), K-frag = contiguous b128 ----
        f32x16 sA[4];
        __builtin_amdgcn_s_setprio(1);
        #pragma unroll
        for (int mt = 0; mt < 4; ++mt) {
            f32x16 z = {};
            #pragma unroll
            for (int kc = 0; kc < 4; ++kc) {
                int row = mt * 32 + lc;
                bf16x8 kf = *(const bf16x8*)&ks[row * DIMD + (((2 * kc + hi) ^ (row & 7)) << 3)];
                z = __builtin_amdgcn_mfma_f32_32x32x16_bf16(kf, qf[kc], z, 0, 0, 0);
            }
            sA[mt] = z;
        }
        __builtin_amdgcn_s_setprio(0);

        // ---- unnormalized p = exp2(s); per-lane denominator accumulation ----
        #pragma unroll
        for (int mt = 0; mt < 4; ++mt) {
            #pragma unroll
            for (int e = 0; e < 16; ++e) {
                float p = __builtin_amdgcn_exp2f(sA[mt][e]);
                sA[mt][e] = p;
                sv += p;
            }
        }

        // ---- pf[kb16] = P fragment, straight from acc regs (V pre-permuted) ----
        bf16x8 pf[8];
        #pragma unroll
        for (int kb16 = 0; kb16 < 8; ++kb16) {
            int mt = kb16 >> 1, base = (kb16 & 1) * 8;
            u32x4 pk;
            #pragma unroll
            for (int w2 = 0; w2 < 4; ++w2)
                pk[w2] = cvtpk(sA[mt][base + 2 * w2], sA[mt][base + 2 * w2 + 1]);
            pf[kb16] = __builtin_bit_cast(bf16x8, pk);
        }

        // ---- stage next tile + issue next-next loads BEFORE PV (T14) ----
        if (kb < kb1) {
            STAGE(cur ^ 1);
            if (kb + 1 < kb1) LOADREGS();
        }

        // ---- O^T += Vt P ----
        __builtin_amdgcn_s_setprio(1);
        #pragma unroll
        for (int dmt = 0; dmt < 2; ++dmt) {
            f32x16 o = oacc[dmt];
            #pragma unroll
            for (int kb16 = 0; kb16 < 8; ++kb16) {
                int row = dmt * 32 + lc;
                bf16x8 vf = *(const bf16x8*)&vs[row * BLK + (((2 * kb16 + hi) ^ (row & 7)) << 3)];
                o = __builtin_amdgcn_mfma_f32_32x32x16_bf16(vf, pf[kb16], o, 0, 0, 0);
            }
            oacc[dmt] = o;
        }
        __builtin_amdgcn_s_setprio(0);

        __syncthreads();
        cur ^= 1;
    }

    // ---- epilogue: ONE shuffle for the denominator; d = dmt*32 + 8g + 4hi + m ----
    float l = sv + __shfl_xor(sv, 32, 64);
    float inv = 1.0f / l;
    float* orow = out + (size_t)qrow * ROWSTRIDE + h * DIMD;
    #pragma unroll
    for (int dmt = 0; dmt < 2; ++dmt) {
        #pragma unroll
        for (int g = 0; g < 4; ++g) {
            float4 rv;
            rv.x = oacc[dmt][4 * g + 0] * inv;
            rv.y = oacc[dmt][4 * g + 1] * inv;
            rv.z = oacc[dmt][4 * g + 2] * inv;
            rv.w = oacc[dmt][4 * g + 3] * inv;
            *(float4*)(orow + dmt * 32 + g * 8 + hi * 4) = rv;
        }
    }
#undef LOADREGS
#undef STAGE
}

// ---------------- fallback (fp32 direct, round-1 proven) ----------------
extern "C" __global__ __launch_bounds__(512)
void bsattn_fallback(const float* __restrict__ q,
                     const float* __restrict__ k,
                     const float* __restrict__ v,
                     float* __restrict__ out)
{
    __shared__ short Ksh[BLK * K_LDF];
    __shared__ short Vsh[DIMD * V_LD];
    __shared__ short Psh[8][16 * P_LD];

    const int r = blockIdx.x;
    const int h = blockIdx.y;
    const int t = threadIdx.x;
    const int w = t >> 6;
    const int lane = t & 63;
    const int lr = lane >> 4;
    const int lc = lane & 15;

    const int krow = t >> 4;
    const int kcol = (t & 15) * 4;
    const int vd  = t & 63;
    const int vkg = t >> 6;

    const int qrow_l = w * 16 + lc;
    const float* qp = q + (size_t)(r * BLK + qrow_l) * ROWSTRIDE + h * DIMD + lr * 8;
    bf16x8 qf[2];
    #pragma unroll
    for (int kc = 0; kc < 2; ++kc) {
        float4 a = *(const float4*)(qp + kc * 32);
        float4 b = *(const float4*)(qp + kc * 32 + 4);
        bf16x8 f;
        f[0] = f2bf(a.x); f[1] = f2bf(a.y); f[2] = f2bf(a.z); f[3] = f2bf(a.w);
        f[4] = f2bf(b.x); f[5] = f2bf(b.y); f[6] = f2bf(b.z); f[7] = f2bf(b.w);
        qf[kc] = f;
    }

    f32x4 acc[4] = {};
    float m_run[4], l_run[4];
    #pragma unroll
    for (int i = 0; i < 4; ++i) { m_run[i] = -1e30f; l_run[i] = 0.0f; }

    const int kb0 = (r - BPS > 0) ? (r - BPS) : 0;
    const int kb1 = (r + BPS < NROW - 1) ? (r + BPS) : (NROW - 1);

    for (int kb = kb0; kb <= kb1; ++kb) {
        __syncthreads();
        const float* kp = k + (size_t)(kb * BLK) * ROWSTRIDE + h * DIMD;
        const float* vp = v + (size_t)(kb * BLK) * ROWSTRIDE + h * DIMD;

        #pragma unroll
        for (int i = 0; i < 4; ++i) {
            float4 kv = *(const float4*)(kp + (size_t)(i * 32 + krow) * ROWSTRIDE + kcol);
            short4 ks;
            ks.x = f2bf(kv.x); ks.y = f2bf(kv.y); ks.z = f2bf(kv.z); ks.w = f2bf(kv.w);
            *(short4*)&Ksh[(i * 32 + krow) * K_LDF + kcol] = ks;

            const float* vr = vp + (size_t)(i * 32 + vkg * 4) * ROWSTRIDE + vd;
            short4 vs;
            vs.x = f2bf(vr[0 * ROWSTRIDE]);
            vs.y = f2bf(vr[1 * ROWSTRIDE]);
            vs.z = f2bf(vr[2 * ROWSTRIDE]);
            vs.w = f2bf(vr[3 * ROWSTRIDE]);
            *(short4*)&Vsh[vd * V_LD + i * 32 + vkg * 4] = vs;
        }
        __syncthreads();

        f32x4 s[8];
        #pragma unroll
        for (int n = 0; n < 8; ++n) {
            f32x4 z = {};
            #pragma unroll
            for (int kc = 0; kc < 2; ++kc) {
                bf16x8 kf = *(const bf16x8*)&Ksh[(n * 16 + lc) * K_LDF + kc * 32 + lr * 8];
                z = __builtin_amdgcn_mfma_f32_16x16x32_bf16(qf[kc], kf, z, 0, 0, 0);
            }
            s[n] = z * SCALE;
        }

        #pragma unroll
        for (int rr = 0; rr < 4; ++rr) {
            float mx = s[0][rr];
            #pragma unroll
            for (int n = 1; n < 8; ++n) mx = fmaxf(mx, s[n][rr]);
            #pragma unroll
            for (int off = 1; off < 16; off <<= 1)
                mx = fmaxf(mx, __shfl_xor(mx, off, 64));
            float mnew = fmaxf(m_run[rr], mx);
            float al = exp2f((m_run[rr] - mnew) * L2E);
            m_run[rr] = mnew;
            float sum = 0.0f;
            #pragma unroll
            for (int n = 0; n < 8; ++n) {
                float p = exp2f((s[n][rr] - mnew) * L2E);
                s[n][rr] = p;
                sum += p;
            }
            #pragma unroll
            for (int off = 1; off < 16; off <<= 1)
                sum += __shfl_xor(sum, off, 64);
            l_run[rr] = l_run[rr] * al + sum;
            #pragma unroll
            for (int dn = 0; dn < 4; ++dn) acc[dn][rr] *= al;
        }

        short* pw = &Psh[w][0];
        #pragma unroll
        for (int n = 0; n < 8; ++n) {
            #pragma unroll
            for (int rr = 0; rr < 4; ++rr) {
                pw[(lr * 4 + rr) * P_LD + n * 16 + lc] = f2bf(s[n][rr]);
            }
        }

        #pragma unroll
        for (int dn = 0; dn < 4; ++dn) {
            f32x4 o = acc[dn];
            #pragma unroll
            for (int kc = 0; kc < 4; ++kc) {
                bf16x8 pfr = *(const bf16x8*)&pw[lc * P_LD + kc * 32 + lr * 8];
                bf16x8 vf = *(const bf16x8*)&Vsh[(dn * 16 + lc) * V_LD + kc * 32 + lr * 8];
                o = __builtin_amdgcn_mfma_f32_16x16x32_bf16(pfr, vf, o, 0, 0, 0);
            }
            acc[dn] = o;
        }
    }

    float* op = out + (size_t)(r * BLK + w * 16) * ROWSTRIDE + h * DIMD;
    #pragma unroll
    for (int rr = 0; rr < 4; ++rr) {
        float inv = 1.0f / l_run[rr];
        float* orow = op + (size_t)(lr * 4 + rr) * ROWSTRIDE;
        #pragma unroll
        for (int dn = 0; dn < 4; ++dn) {
            orow[dn * 16 + lc] = acc[dn][rr] * inv;
        }
    }
}

extern "C" void kernel_launch(void* const* d_in, const int* in_sizes, int n_in,
                              void* d_out, int out_size, void* d_ws, size_t ws_size,
                              hipStream_t stream) {
    const float* q = (const float*)d_in[0];
    const float* k = (const float*)d_in[1];
    const float* v = (const float*)d_in[2];
    float* out = (float*)d_out;

    if (ws_size >= (size_t)WS_NEEDED) {
        short* Kb = (short*)d_ws;
        short* Vt = Kb + (size_t)NH * HEAD_ELEMS;
        prep_kernel<<<512, 256, 0, stream>>>(k, v, Kb, Vt);
        bsattn_main<<<512, 128, 0, stream>>>(q, Kb, Vt, out);
    } else {
        bsattn_fallback<<<dim3(NROW, NH), 512, 0, stream>>>(q, k, v, out);
    }
}

// Round 14
// 27.093 us; speedup vs baseline: 1.2292x; 1.2292x over previous
//
#include <hip/hip_runtime.h>
#include <hip/hip_bf16.h>

#define NATOM 4096
#define NH 8
#define DIMD 64
#define BLK 128
#define NROW 32
#define BPS 4
#define ROWSTRIDE (NH * DIMD)   // 512 floats
#define SCALE 0.125f
#define L2E 1.4426950408889634f

#define TILE_EL (BLK * DIMD)    // 8192 shorts = 16 KB per K or V tile
#define V_LD 136                // prep scratch only
#define P_LD 136                // fallback only
#define K_LDF 72                // fallback only

#define HEAD_ELEMS (NATOM * DIMD)               // 262144 bf16 per head plane
#define WS_NEEDED  (2u * NH * HEAD_ELEMS * 2u)  // Kb + Vt, bf16

typedef __attribute__((ext_vector_type(8))) short bf16x8;
typedef __attribute__((ext_vector_type(4))) float f32x4;
typedef __attribute__((ext_vector_type(4))) unsigned int u32x4;

__device__ __forceinline__ short f2bf(float x) {
    unsigned int u = __builtin_bit_cast(unsigned int, x);
    unsigned int r = (u + 0x7fffu + ((u >> 16) & 1u)) >> 16;
    return (short)r;
}
__device__ __forceinline__ unsigned int cvtpk(float lo, float hi) {
    unsigned int r;
    asm("v_cvt_pk_bf16_f32 %0, %1, %2" : "=v"(r) : "v"(lo), "v"(hi));
    return r;
}
// Explicit drain of async global_load_lds: its LDS-write completion is
// vmcnt-tracked, and a workgroup fence is not guaranteed to wait vmcnt when
// the loads were issued after the previous barrier (round-13 race).
__device__ __forceinline__ void drain_gll() {
    asm volatile("s_waitcnt vmcnt(0)" ::: "memory");
}

// ---------------- prep kernel: 512 blocks, h-major XCD swizzle ----------------
// Kb: bf16 [h][row][chunk'] with chunk' = chunk ^ (row&7)  (8 chunks of 8 shorts,
//     natural stride 64)  -- bank swizzle baked into GLOBAL layout so main can
//     stage with linear global_load_lds and un-XOR on the LDS read side.
// Vt: bf16 [h][nb][d][chunk'] TILE-MAJOR (16 KB contiguous per key-block);
//     within each tile, logical column c = kc*32+lr*8+j holds key
//     kc*32 + (j>>2)*16 + lr*4 + (j&3) (round-8 proven lane-local PV perm),
//     and chunk' = cc ^ (d&15) bakes the bank swizzle.
extern "C" __global__ __launch_bounds__(256)
void prep_kernel(const float* __restrict__ k, const float* __restrict__ v,
                 short* __restrict__ Kb, short* __restrict__ Vt)
{
    __shared__ short Tr[DIMD * V_LD];
    const int bid  = blockIdx.x;
    const int h    = bid & 7;
    const int part = bid >> 3;          // 0..63
    const int t    = threadIdx.x;

    if (part < 32) {
        const int nb = part;
        #pragma unroll
        for (int i = 0; i < 4; ++i) {
            int idx = i * 256 + t;
            int row = idx >> 3;               // tile-local row
            int c   = idx & 7;                // d-chunk
            int d0  = c * 8;
            int grow = nb * BLK + row;
            const float* src = k + (size_t)grow * ROWSTRIDE + h * DIMD + d0;
            float4 a = *(const float4*)src;
            float4 cc = *(const float4*)(src + 4);
            bf16x8 f;
            f[0] = f2bf(a.x); f[1] = f2bf(a.y); f[2] = f2bf(a.z); f[3] = f2bf(a.w);
            f[4] = f2bf(cc.x); f[5] = f2bf(cc.y); f[6] = f2bf(cc.z); f[7] = f2bf(cc.w);
            *(bf16x8*)(Kb + (size_t)h * HEAD_ELEMS + (size_t)grow * DIMD
                       + ((c ^ (grow & 7)) * 8)) = f;
        }
    } else {
        const int nb = part - 32;
        const int vd = t & 63;
        const int g  = t >> 6;
        const float* vp = v + (size_t)(nb * BLK) * ROWSTRIDE + h * DIMD + vd;
        #pragma unroll
        for (int i = 0; i < 8; ++i) {
            int n4 = i * 16 + g * 4;
            const float* vr = vp + (size_t)n4 * ROWSTRIDE;
            short4 s4;
            s4.x = f2bf(vr[0 * ROWSTRIDE]);
            s4.y = f2bf(vr[1 * ROWSTRIDE]);
            s4.z = f2bf(vr[2 * ROWSTRIDE]);
            s4.w = f2bf(vr[3 * ROWSTRIDE]);
            *(short4*)&Tr[vd * V_LD + n4] = s4;   // Tr column = natural local key
        }
        __syncthreads();
        #pragma unroll
        for (int i = 0; i < 4; ++i) {
            int s  = i * 256 + t;
            int d  = s >> 4;
            int cc = s & 15;                       // logical 8-col chunk
            int kc = cc >> 2;
            int l2 = cc & 3;
            int kA = kc * 32 + l2 * 4;             // keys for j=0..3 (round-8 perm)
            short4 a  = *(const short4*)&Tr[d * V_LD + kA];
            short4 c4 = *(const short4*)&Tr[d * V_LD + kA + 16];  // keys j=4..7
            bf16x8 f;
            f[0] = a.x;  f[1] = a.y;  f[2] = a.z;  f[3] = a.w;
            f[4] = c4.x; f[5] = c4.y; f[6] = c4.z; f[7] = c4.w;
            *(bf16x8*)(Vt + (size_t)h * HEAD_ELEMS + (size_t)nb * TILE_EL
                       + d * BLK + ((cc ^ (d & 15)) * 8)) = f;
        }
    }
}

// ---------------- main kernel: round-8 structure + global_load_lds staging ----------------
// Grid 512 x 256thr, h = bid&7. 2 blocks/CU (64 KB LDS), 8 waves/CU (2/SIMD).
// Staging: 8 async global_load_lds (width 16) per thread per tile, linear LDS,
// XOR-swizzle applied on the read side (baked into global layout by prep).
// Double-buffered, ONE barrier/iter; tile kb+2 issued right after the barrier.
// EXPLICIT vmcnt(0) drain before every barrier (round-13 race fix).
extern "C" __global__ __launch_bounds__(256)
void bsattn_main(const float* __restrict__ q,
                 const short* __restrict__ Kb,
                 const short* __restrict__ Vt,
                 float* __restrict__ out)
{
    __shared__ short Ksh[2][TILE_EL];      // 2 x 16 KB
    __shared__ short Vsh[2][TILE_EL];      // 2 x 16 KB

    const int bid = blockIdx.x;
    const int h   = bid & 7;
    const int br  = bid >> 3;         // 64-row query block, 0..63
    const int r   = br >> 1;          // 128-row band block
    const int t   = threadIdx.x;
    const int w   = t >> 6;
    const int lane = t & 63;
    const int lr = lane >> 4;
    const int lc = lane & 15;

    // ---- Q fragments (SCALE*L2E folded); B-layout: q = lc, d = kc*32 + lr*8 + j ----
    const int qbase = br * 64 + w * 16;
    const float* qp = q + (size_t)(qbase + lc) * ROWSTRIDE + h * DIMD + lr * 8;
    bf16x8 qf[2];
    #pragma unroll
    for (int kc = 0; kc < 2; ++kc) {
        float4 a = *(const float4*)(qp + kc * 32);
        float4 b = *(const float4*)(qp + kc * 32 + 4);
        bf16x8 f;
        f[0] = f2bf(a.x * (SCALE * L2E)); f[1] = f2bf(a.y * (SCALE * L2E));
        f[2] = f2bf(a.z * (SCALE * L2E)); f[3] = f2bf(a.w * (SCALE * L2E));
        f[4] = f2bf(b.x * (SCALE * L2E)); f[5] = f2bf(b.y * (SCALE * L2E));
        f[6] = f2bf(b.z * (SCALE * L2E)); f[7] = f2bf(b.w * (SCALE * L2E));
        qf[kc] = f;
    }
    bf16x8 onesA;
    #pragma unroll
    for (int i = 0; i < 8; ++i) onesA[i] = (short)0x3F80;   // bf16 1.0

    const short* kbase = Kb + (size_t)h * HEAD_ELEMS;
    const short* vbase = Vt + (size_t)h * HEAD_ELEMS;

    f32x4 acc[4] = {};
    f32x4 lacc = {};

    const int kb0 = (r - BPS > 0) ? (r - BPS) : 0;
    const int kb1 = (r + BPS < NROW - 1) ? (r + BPS) : (NROW - 1);

    const short* kt = kbase + (size_t)kb0 * TILE_EL;   // K tiles contiguous (rows)
    const short* vt = vbase + (size_t)kb0 * TILE_EL;   // V tiles contiguous (tile-major)

#define ISSUE(buf, off)                                                           \
    {                                                                             \
        const short* kq = kt + (size_t)(off) * TILE_EL;                           \
        const short* vq = vt + (size_t)(off) * TILE_EL;                           \
        _Pragma("unroll")                                                         \
        for (int i = 0; i < 4; ++i) {                                             \
            int idx = i * 256 + t;                                                \
            __builtin_amdgcn_global_load_lds(                                     \
                (const __attribute__((address_space(1))) unsigned int*)(kq + idx * 8), \
                (__attribute__((address_space(3))) unsigned int*)(&Ksh[buf][idx * 8]), \
                16, 0, 0);                                                        \
            __builtin_amdgcn_global_load_lds(                                     \
                (const __attribute__((address_space(1))) unsigned int*)(vq + idx * 8), \
                (__attribute__((address_space(3))) unsigned int*)(&Vsh[buf][idx * 8]), \
                16, 0, 0);                                                        \
        }                                                                         \
    }

    ISSUE(0, 0);
    if (kb0 < kb1) ISSUE(1, 1);
    drain_gll();                           // all prologue tiles landed
    __syncthreads();

    int cur = 0;
    for (int kb = kb0; kb <= kb1; ++kb) {
        const short* ks = &Ksh[cur][0];
        const short* vs = &Vsh[cur][0];

        // ---- S2 = (q·k)*SCALE*L2E (log2 domain); K chunk un-XOR on read ----
        f32x4 s[8];
        __builtin_amdgcn_s_setprio(1);
        #pragma unroll
        for (int mt = 0; mt < 8; ++mt) {
            f32x4 z = {};
            int row = mt * 16 + lc;
            #pragma unroll
            for (int kc = 0; kc < 2; ++kc) {
                bf16x8 kf = *(const bf16x8*)&ks[row * DIMD + (((kc * 4 + lr) ^ (row & 7)) * 8)];
                z = __builtin_amdgcn_mfma_f32_16x16x32_bf16(kf, qf[kc], z, 0, 0, 0);
            }
            s[mt] = z;
        }
        __builtin_amdgcn_s_setprio(0);

        // ---- unnormalized softmax: p = exp2(s), no max needed ----
        #pragma unroll
        for (int mt = 0; mt < 8; ++mt) {
            #pragma unroll
            for (int e = 0; e < 4; ++e)
                s[mt][e] = __builtin_amdgcn_exp2f(s[mt][e]);
        }

        // ---- pf: lane-local pack (V columns pre-permuted) ----
        bf16x8 pf[4];
        #pragma unroll
        for (int kc = 0; kc < 4; ++kc) {
            u32x4 pk;
            pk[0] = cvtpk(s[2 * kc][0],     s[2 * kc][1]);
            pk[1] = cvtpk(s[2 * kc][2],     s[2 * kc][3]);
            pk[2] = cvtpk(s[2 * kc + 1][0], s[2 * kc + 1][1]);
            pk[3] = cvtpk(s[2 * kc + 1][2], s[2 * kc + 1][3]);
            pf[kc] = __builtin_bit_cast(bf16x8, pk);
        }

        // ---- O^T += Vt P ; l += 1^T P (ones-trick, MFMA pipe); V un-XOR on read ----
        __builtin_amdgcn_s_setprio(1);
        #pragma unroll
        for (int dn = 0; dn < 4; ++dn) {
            f32x4 o = acc[dn];
            int d = dn * 16 + lc;
            #pragma unroll
            for (int kc = 0; kc < 4; ++kc) {
                bf16x8 vf = *(const bf16x8*)&vs[d * BLK + (((kc * 4 + lr) ^ (d & 15)) * 8)];
                o = __builtin_amdgcn_mfma_f32_16x16x32_bf16(vf, pf[kc], o, 0, 0, 0);
            }
            acc[dn] = o;
        }
        #pragma unroll
        for (int kc = 0; kc < 4; ++kc)
            lacc = __builtin_amdgcn_mfma_f32_16x16x32_bf16(onesA, pf[kc], lacc, 0, 0, 0);
        __builtin_amdgcn_s_setprio(0);

        drain_gll();                       // tile kb+1's async loads fully landed
        __syncthreads();                   // all waves' LDS reads of buf cur done
        if (kb + 2 <= kb1) ISSUE(cur, kb - kb0 + 2);   // into the buffer just consumed
        cur ^= 1;
    }

    // ---- epilogue: q = lc, d = dn*16 + lr*4 + reg -> float4 stores ----
    float inv = 1.0f / lacc[0];
    float* orow = out + (size_t)(qbase + lc) * ROWSTRIDE + h * DIMD;
    #pragma unroll
    for (int dn = 0; dn < 4; ++dn) {
        f32x4 rv;
        rv[0] = acc[dn][0] * inv; rv[1] = acc[dn][1] * inv;
        rv[2] = acc[dn][2] * inv; rv[3] = acc[dn][3] * inv;
        *(float4*)(orow + dn * 16 + lr * 4) = *(float4*)&rv;
    }
#undef ISSUE
}

// ---------------- fallback (fp32 direct, round-1 proven) ----------------
extern "C" __global__ __launch_bounds__(512)
void bsattn_fallback(const float* __restrict__ q,
                     const float* __restrict__ k,
                     const float* __restrict__ v,
                     float* __restrict__ out)
{
    __shared__ short Ksh[BLK * K_LDF];
    __shared__ short Vsh[DIMD * V_LD];
    __shared__ short Psh[8][16 * P_LD];

    const int r = blockIdx.x;
    const int h = blockIdx.y;
    const int t = threadIdx.x;
    const int w = t >> 6;
    const int lane = t & 63;
    const int lr = lane >> 4;
    const int lc = lane & 15;

    const int krow = t >> 4;
    const int kcol = (t & 15) * 4;
    const int vd  = t & 63;
    const int vkg = t >> 6;

    const int qrow_l = w * 16 + lc;
    const float* qp = q + (size_t)(r * BLK + qrow_l) * ROWSTRIDE + h * DIMD + lr * 8;
    bf16x8 qf[2];
    #pragma unroll
    for (int kc = 0; kc < 2; ++kc) {
        float4 a = *(const float4*)(qp + kc * 32);
        float4 b = *(const float4*)(qp + kc * 32 + 4);
        bf16x8 f;
        f[0] = f2bf(a.x); f[1] = f2bf(a.y); f[2] = f2bf(a.z); f[3] = f2bf(a.w);
        f[4] = f2bf(b.x); f[5] = f2bf(b.y); f[6] = f2bf(b.z); f[7] = f2bf(b.w);
        qf[kc] = f;
    }

    f32x4 acc[4] = {};
    float m_run[4], l_run[4];
    #pragma unroll
    for (int i = 0; i < 4; ++i) { m_run[i] = -1e30f; l_run[i] = 0.0f; }

    const int kb0 = (r - BPS > 0) ? (r - BPS) : 0;
    const int kb1 = (r + BPS < NROW - 1) ? (r + BPS) : (NROW - 1);

    for (int kb = kb0; kb <= kb1; ++kb) {
        __syncthreads();
        const float* kp = k + (size_t)(kb * BLK) * ROWSTRIDE + h * DIMD;
        const float* vp = v + (size_t)(kb * BLK) * ROWSTRIDE + h * DIMD;

        #pragma unroll
        for (int i = 0; i < 4; ++i) {
            float4 kv = *(const float4*)(kp + (size_t)(i * 32 + krow) * ROWSTRIDE + kcol);
            short4 ks;
            ks.x = f2bf(kv.x); ks.y = f2bf(kv.y); ks.z = f2bf(kv.z); ks.w = f2bf(kv.w);
            *(short4*)&Ksh[(i * 32 + krow) * K_LDF + kcol] = ks;

            const float* vr = vp + (size_t)(i * 32 + vkg * 4) * ROWSTRIDE + vd;
            short4 vs;
            vs.x = f2bf(vr[0 * ROWSTRIDE]);
            vs.y = f2bf(vr[1 * ROWSTRIDE]);
            vs.z = f2bf(vr[2 * ROWSTRIDE]);
            vs.w = f2bf(vr[3 * ROWSTRIDE]);
            *(short4*)&Vsh[vd * V_LD + i * 32 + vkg * 4] = vs;
        }
        __syncthreads();

        f32x4 s[8];
        #pragma unroll
        for (int n = 0; n < 8; ++n) {
            f32x4 z = {};
            #pragma unroll
            for (int kc = 0; kc < 2; ++kc) {
                bf16x8 kf = *(const bf16x8*)&Ksh[(n * 16 + lc) * K_LDF + kc * 32 + lr * 8];
                z = __builtin_amdgcn_mfma_f32_16x16x32_bf16(qf[kc], kf, z, 0, 0, 0);
            }
            s[n] = z * SCALE;
        }

        #pragma unroll
        for (int rr = 0; rr < 4; ++rr) {
            float mx = s[0][rr];
            #pragma unroll
            for (int n = 1; n < 8; ++n) mx = fmaxf(mx, s[n][rr]);
            #pragma unroll
            for (int off = 1; off < 16; off <<= 1)
                mx = fmaxf(mx, __shfl_xor(mx, off, 64));
            float mnew = fmaxf(m_run[rr], mx);
            float al = exp2f((m_run[rr] - mnew) * L2E);
            m_run[rr] = mnew;
            float sum = 0.0f;
            #pragma unroll
            for (int n = 0; n < 8; ++n) {
                float p = exp2f((s[n][rr] - mnew) * L2E);
                s[n][rr] = p;
                sum += p;
            }
            #pragma unroll
            for (int off = 1; off < 16; off <<= 1)
                sum += __shfl_xor(sum, off, 64);
            l_run[rr] = l_run[rr] * al + sum;
            #pragma unroll
            for (int dn = 0; dn < 4; ++dn) acc[dn][rr] *= al;
        }

        short* pw = &Psh[w][0];
        #pragma unroll
        for (int n = 0; n < 8; ++n) {
            #pragma unroll
            for (int rr = 0; rr < 4; ++rr) {
                pw[(lr * 4 + rr) * P_LD + n * 16 + lc] = f2bf(s[n][rr]);
            }
        }

        #pragma unroll
        for (int dn = 0; dn < 4; ++dn) {
            f32x4 o = acc[dn];
            #pragma unroll
            for (int kc = 0; kc < 4; ++kc) {
                bf16x8 pfr = *(const bf16x8*)&pw[lc * P_LD + kc * 32 + lr * 8];
                bf16x8 vf = *(const bf16x8*)&Vsh[(dn * 16 + lc) * V_LD + kc * 32 + lr * 8];
                o = __builtin_amdgcn_mfma_f32_16x16x32_bf16(pfr, vf, o, 0, 0, 0);
            }
            acc[dn] = o;
        }
    }

    float* op = out + (size_t)(r * BLK + w * 16) * ROWSTRIDE + h * DIMD;
    #pragma unroll
    for (int rr = 0; rr < 4; ++rr) {
        float inv = 1.0f / l_run[rr];
        float* orow = op + (size_t)(lr * 4 + rr) * ROWSTRIDE;
        #pragma unroll
        for (int dn = 0; dn < 4; ++dn) {
            orow[dn * 16 + lc] = acc[dn][rr] * inv;
        }
    }
}

extern "C" void kernel_launch(void* const* d_in, const int* in_sizes, int n_in,
                              void* d_out, int out_size, void* d_ws, size_t ws_size,
                              hipStream_t stream) {
    const float* q = (const float*)d_in[0];
    const float* k = (const float*)d_in[1];
    const float* v = (const float*)d_in[2];
    float* out = (float*)d_out;

    if (ws_size >= (size_t)WS_NEEDED) {
        short* Kb = (short*)d_ws;
        short* Vt = Kb + (size_t)NH * HEAD_ELEMS;
        prep_kernel<<<512, 256, 0, stream>>>(k, v, Kb, Vt);
        bsattn_main<<<512, 256, 0, stream>>>(q, Kb, Vt, out);
    } else {
        bsattn_fallback<<<dim3(NROW, NH), 512, 0, stream>>>(q, k, v, out);
    }
}

// Round 15
// 26.548 us; speedup vs baseline: 1.2544x; 1.0205x over previous
//
#include <hip/hip_runtime.h>
#include <hip/hip_bf16.h>

#define NATOM 4096
#define NH 8
#define DIMD 64
#define BLK 128
#define NROW 32
#define BPS 4
#define ROWSTRIDE (NH * DIMD)   // 512 floats
#define SCALE 0.125f
#define L2E 1.4426950408889634f

#define TILE64 (64 * DIMD)      // 4096 shorts = 8 KB per 64-key K or V tile
#define V_LD 136                // prep scratch only
#define P_LD 136                // fallback only
#define K_LDF 72                // fallback only

#define HEAD_ELEMS (NATOM * DIMD)               // 262144 bf16 per head plane
#define WS_NEEDED  (2u * NH * HEAD_ELEMS * 2u)  // Kb + Vt, bf16

typedef __attribute__((ext_vector_type(8))) short bf16x8;
typedef __attribute__((ext_vector_type(4))) float f32x4;
typedef __attribute__((ext_vector_type(4))) unsigned int u32x4;

__device__ __forceinline__ short f2bf(float x) {
    unsigned int u = __builtin_bit_cast(unsigned int, x);
    unsigned int r = (u + 0x7fffu + ((u >> 16) & 1u)) >> 16;
    return (short)r;
}
__device__ __forceinline__ unsigned int cvtpk(float lo, float hi) {
    unsigned int r;
    asm("v_cvt_pk_bf16_f32 %0, %1, %2" : "=v"(r) : "v"(lo), "v"(hi));
    return r;
}
// Explicit drain of async global_load_lds (vmcnt-tracked LDS writes; a
// workgroup fence alone does not reliably wait them across barriers).
__device__ __forceinline__ void drain_gll() {
    asm volatile("s_waitcnt vmcnt(0)" ::: "memory");
}

// ---------------- prep kernel: 512 blocks, h-major XCD swizzle ----------------
// Kb: bf16 [h][grow][chunk'] with chunk' = chunk ^ (grow&7) (8 chunks of 8
//     shorts, natural stride 64) -- bank swizzle baked into GLOBAL layout so
//     main stages with linear global_load_lds and un-XORs on the LDS read.
//     Tile-size-agnostic (64-key tiles are 8-row-aligned).
// Vt: bf16 [h][vb][d][chunk'] TILE-MAJOR per 64-key block vb (8 KB/tile);
//     within a tile, logical chunk cc = kc*4+lr (kc 0..1) holds keys
//     kc*32 + (j>>2)*16 + lr*4 + (j&3)  (lane-local PV fragment, round-8
//     proven), and chunk' = cc ^ (d&7) bakes the bank swizzle.
extern "C" __global__ __launch_bounds__(256)
void prep_kernel(const float* __restrict__ k, const float* __restrict__ v,
                 short* __restrict__ Kb, short* __restrict__ Vt)
{
    __shared__ short Tr[DIMD * V_LD];
    const int bid  = blockIdx.x;
    const int h    = bid & 7;
    const int part = bid >> 3;          // 0..63
    const int t    = threadIdx.x;

    if (part < 32) {
        const int nb = part;            // 128-row K chunk
        #pragma unroll
        for (int i = 0; i < 4; ++i) {
            int idx = i * 256 + t;
            int row = idx >> 3;
            int c   = idx & 7;
            int d0  = c * 8;
            int grow = nb * BLK + row;
            const float* src = k + (size_t)grow * ROWSTRIDE + h * DIMD + d0;
            float4 a = *(const float4*)src;
            float4 cc = *(const float4*)(src + 4);
            bf16x8 f;
            f[0] = f2bf(a.x); f[1] = f2bf(a.y); f[2] = f2bf(a.z); f[3] = f2bf(a.w);
            f[4] = f2bf(cc.x); f[5] = f2bf(cc.y); f[6] = f2bf(cc.z); f[7] = f2bf(cc.w);
            *(bf16x8*)(Kb + (size_t)h * HEAD_ELEMS + (size_t)grow * DIMD
                       + ((c ^ (grow & 7)) * 8)) = f;
        }
    } else {
        const int nb = part - 32;       // 128-key V block -> two 64-key tiles
        const int vd = t & 63;
        const int g  = t >> 6;
        const float* vp = v + (size_t)(nb * BLK) * ROWSTRIDE + h * DIMD + vd;
        #pragma unroll
        for (int i = 0; i < 8; ++i) {
            int n4 = i * 16 + g * 4;
            const float* vr = vp + (size_t)n4 * ROWSTRIDE;
            short4 s4;
            s4.x = f2bf(vr[0 * ROWSTRIDE]);
            s4.y = f2bf(vr[1 * ROWSTRIDE]);
            s4.z = f2bf(vr[2 * ROWSTRIDE]);
            s4.w = f2bf(vr[3 * ROWSTRIDE]);
            *(short4*)&Tr[vd * V_LD + n4] = s4;   // Tr column = key within 128-block
        }
        __syncthreads();
        #pragma unroll
        for (int i = 0; i < 4; ++i) {
            int s    = i * 256 + t;
            int d    = s >> 4;
            int cc16 = s & 15;
            int half = cc16 >> 3;                  // which 64-key tile
            int cc   = cc16 & 7;                   // logical chunk in tile
            int kc   = cc >> 2;
            int l2   = cc & 3;
            int kA   = half * 64 + kc * 32 + l2 * 4;   // keys j=0..3 in Tr
            short4 a  = *(const short4*)&Tr[d * V_LD + kA];
            short4 c4 = *(const short4*)&Tr[d * V_LD + kA + 16];  // keys j=4..7
            bf16x8 f;
            f[0] = a.x;  f[1] = a.y;  f[2] = a.z;  f[3] = a.w;
            f[4] = c4.x; f[5] = c4.y; f[6] = c4.z; f[7] = c4.w;
            *(bf16x8*)(Vt + (size_t)h * HEAD_ELEMS + (size_t)(2 * nb + half) * TILE64
                       + d * 64 + ((cc ^ (d & 7)) * 8)) = f;
        }
    }
}

// ---------------- main kernel: KVBLK=64, 4 blocks/CU, 16 waves/CU ----------------
// Grid 512 x 256thr, h = bid&7. LDS 32 KB/block -> 4 blocks/CU (4 waves/SIMD):
// 4 independent barrier groups per CU hide each other's barrier drains.
// Staging: 4 async global_load_lds (width 16)/thread/tile, linear LDS,
// XOR-swizzle baked into global layout, un-XOR on read. Double-buffered,
// ONE barrier/iter, explicit vmcnt(0) drain before every barrier.
// S^T = mfma(K,Q): lane holds S[key = mt*16 + lr*4 + e][q = lc]   (mt 0..3)
// PV: pf[kc] = {s[2kc][0..3], s[2kc+1][0..3]} lane-local (V pre-permuted), kc 0..1
// O^T = mfma(Vt,P): lane holds O[q = lc][d = dn*16 + lr*4 + reg]
// Unnormalized exp2 (log2 domain, SCALE*L2E in Q); denominator via ones-MFMA.
extern "C" __global__ __launch_bounds__(256, 4)
void bsattn_main(const float* __restrict__ q,
                 const short* __restrict__ Kb,
                 const short* __restrict__ Vt,
                 float* __restrict__ out)
{
    __shared__ short Ksh[2][TILE64];      // 2 x 8 KB
    __shared__ short Vsh[2][TILE64];      // 2 x 8 KB

    const int bid = blockIdx.x;
    const int h   = bid & 7;
    const int br  = bid >> 3;         // 64-row query block, 0..63
    const int r   = br >> 1;          // 128-row band block
    const int t   = threadIdx.x;
    const int w   = t >> 6;
    const int lane = t & 63;
    const int lr = lane >> 4;
    const int lc = lane & 15;

    // ---- Q fragments (SCALE*L2E folded); B-layout: q = lc, d = kc*32 + lr*8 + j ----
    const int qbase = br * 64 + w * 16;
    const float* qp = q + (size_t)(qbase + lc) * ROWSTRIDE + h * DIMD + lr * 8;
    bf16x8 qf[2];
    #pragma unroll
    for (int kc = 0; kc < 2; ++kc) {
        float4 a = *(const float4*)(qp + kc * 32);
        float4 b = *(const float4*)(qp + kc * 32 + 4);
        bf16x8 f;
        f[0] = f2bf(a.x * (SCALE * L2E)); f[1] = f2bf(a.y * (SCALE * L2E));
        f[2] = f2bf(a.z * (SCALE * L2E)); f[3] = f2bf(a.w * (SCALE * L2E));
        f[4] = f2bf(b.x * (SCALE * L2E)); f[5] = f2bf(b.y * (SCALE * L2E));
        f[6] = f2bf(b.z * (SCALE * L2E)); f[7] = f2bf(b.w * (SCALE * L2E));
        qf[kc] = f;
    }
    bf16x8 onesA;
    #pragma unroll
    for (int i = 0; i < 8; ++i) onesA[i] = (short)0x3F80;   // bf16 1.0

    const short* kbase = Kb + (size_t)h * HEAD_ELEMS;
    const short* vbase = Vt + (size_t)h * HEAD_ELEMS;

    f32x4 acc[4] = {};
    f32x4 lacc = {};

    // band in 64-key tile units
    const int r0 = (r - BPS > 0) ? (r - BPS) : 0;
    const int r1 = (r + BPS < NROW - 1) ? (r + BPS) : (NROW - 1);
    const int kb0 = r0 * 2;
    const int kb1 = r1 * 2 + 1;

    const short* kt = kbase + (size_t)kb0 * TILE64;
    const short* vt = vbase + (size_t)kb0 * TILE64;

#define ISSUE(buf, off)                                                           \
    {                                                                             \
        const short* kq = kt + (size_t)(off) * TILE64;                            \
        const short* vq = vt + (size_t)(off) * TILE64;                            \
        _Pragma("unroll")                                                         \
        for (int i = 0; i < 2; ++i) {                                             \
            int idx = i * 256 + t;                                                \
            __builtin_amdgcn_global_load_lds(                                     \
                (const __attribute__((address_space(1))) unsigned int*)(kq + idx * 8), \
                (__attribute__((address_space(3))) unsigned int*)(&Ksh[buf][idx * 8]), \
                16, 0, 0);                                                        \
            __builtin_amdgcn_global_load_lds(                                     \
                (const __attribute__((address_space(1))) unsigned int*)(vq + idx * 8), \
                (__attribute__((address_space(3))) unsigned int*)(&Vsh[buf][idx * 8]), \
                16, 0, 0);                                                        \
        }                                                                         \
    }

    ISSUE(0, 0);
    ISSUE(1, 1);                           // band always has >= 10 tiles
    drain_gll();
    __syncthreads();

    int cur = 0;
    for (int kb = kb0; kb <= kb1; ++kb) {
        const short* ks = &Ksh[cur][0];
        const short* vs = &Vsh[cur][0];

        // ---- S2 = (q·k)*SCALE*L2E (log2 domain); K chunk un-XOR on read ----
        f32x4 s[4];
        __builtin_amdgcn_s_setprio(1);
        #pragma unroll
        for (int mt = 0; mt < 4; ++mt) {
            f32x4 z = {};
            int row = mt * 16 + lc;
            #pragma unroll
            for (int kc = 0; kc < 2; ++kc) {
                bf16x8 kf = *(const bf16x8*)&ks[row * DIMD + (((kc * 4 + lr) ^ (row & 7)) * 8)];
                z = __builtin_amdgcn_mfma_f32_16x16x32_bf16(kf, qf[kc], z, 0, 0, 0);
            }
            s[mt] = z;
        }
        __builtin_amdgcn_s_setprio(0);

        // ---- unnormalized softmax: p = exp2(s) ----
        #pragma unroll
        for (int mt = 0; mt < 4; ++mt) {
            #pragma unroll
            for (int e = 0; e < 4; ++e)
                s[mt][e] = __builtin_amdgcn_exp2f(s[mt][e]);
        }

        // ---- pf: lane-local pack (V columns pre-permuted) ----
        bf16x8 pf[2];
        #pragma unroll
        for (int kc = 0; kc < 2; ++kc) {
            u32x4 pk;
            pk[0] = cvtpk(s[2 * kc][0],     s[2 * kc][1]);
            pk[1] = cvtpk(s[2 * kc][2],     s[2 * kc][3]);
            pk[2] = cvtpk(s[2 * kc + 1][0], s[2 * kc + 1][1]);
            pk[3] = cvtpk(s[2 * kc + 1][2], s[2 * kc + 1][3]);
            pf[kc] = __builtin_bit_cast(bf16x8, pk);
        }

        // ---- O^T += Vt P ; l += 1^T P ; V chunk un-XOR on read ----
        __builtin_amdgcn_s_setprio(1);
        #pragma unroll
        for (int dn = 0; dn < 4; ++dn) {
            f32x4 o = acc[dn];
            int d = dn * 16 + lc;
            #pragma unroll
            for (int kc = 0; kc < 2; ++kc) {
                bf16x8 vf = *(const bf16x8*)&vs[d * 64 + (((kc * 4 + lr) ^ (d & 7)) * 8)];
                o = __builtin_amdgcn_mfma_f32_16x16x32_bf16(vf, pf[kc], o, 0, 0, 0);
            }
            acc[dn] = o;
        }
        #pragma unroll
        for (int kc = 0; kc < 2; ++kc)
            lacc = __builtin_amdgcn_mfma_f32_16x16x32_bf16(onesA, pf[kc], lacc, 0, 0, 0);
        __builtin_amdgcn_s_setprio(0);

        drain_gll();                       // tile kb+1's async loads landed
        __syncthreads();                   // all waves' reads of buf cur done
        if (kb + 2 <= kb1) ISSUE(cur, kb - kb0 + 2);
        cur ^= 1;
    }

    // ---- epilogue: q = lc, d = dn*16 + lr*4 + reg -> float4 stores ----
    float inv = 1.0f / lacc[0];
    float* orow = out + (size_t)(qbase + lc) * ROWSTRIDE + h * DIMD;
    #pragma unroll
    for (int dn = 0; dn < 4; ++dn) {
        f32x4 rv;
        rv[0] = acc[dn][0] * inv; rv[1] = acc[dn][1] * inv;
        rv[2] = acc[dn][2] * inv; rv[3] = acc[dn][3] * inv;
        *(float4*)(orow + dn * 16 + lr * 4) = *(float4*)&rv;
    }
#undef ISSUE
}

// ---------------- fallback (fp32 direct, round-1 proven) ----------------
extern "C" __global__ __launch_bounds__(512)
void bsattn_fallback(const float* __restrict__ q,
                     const float* __restrict__ k,
                     const float* __restrict__ v,
                     float* __restrict__ out)
{
    __shared__ short Ksh[BLK * K_LDF];
    __shared__ short Vsh[DIMD * V_LD];
    __shared__ short Psh[8][16 * P_LD];

    const int r = blockIdx.x;
    const int h = blockIdx.y;
    const int t = threadIdx.x;
    const int w = t >> 6;
    const int lane = t & 63;
    const int lr = lane >> 4;
    const int lc = lane & 15;

    const int krow = t >> 4;
    const int kcol = (t & 15) * 4;
    const int vd  = t & 63;
    const int vkg = t >> 6;

    const int qrow_l = w * 16 + lc;
    const float* qp = q + (size_t)(r * BLK + qrow_l) * ROWSTRIDE + h * DIMD + lr * 8;
    bf16x8 qf[2];
    #pragma unroll
    for (int kc = 0; kc < 2; ++kc) {
        float4 a = *(const float4*)(qp + kc * 32);
        float4 b = *(const float4*)(qp + kc * 32 + 4);
        bf16x8 f;
        f[0] = f2bf(a.x); f[1] = f2bf(a.y); f[2] = f2bf(a.z); f[3] = f2bf(a.w);
        f[4] = f2bf(b.x); f[5] = f2bf(b.y); f[6] = f2bf(b.z); f[7] = f2bf(b.w);
        qf[kc] = f;
    }

    f32x4 acc[4] = {};
    float m_run[4], l_run[4];
    #pragma unroll
    for (int i = 0; i < 4; ++i) { m_run[i] = -1e30f; l_run[i] = 0.0f; }

    const int kb0 = (r - BPS > 0) ? (r - BPS) : 0;
    const int kb1 = (r + BPS < NROW - 1) ? (r + BPS) : (NROW - 1);

    for (int kb = kb0; kb <= kb1; ++kb) {
        __syncthreads();
        const float* kp = k + (size_t)(kb * BLK) * ROWSTRIDE + h * DIMD;
        const float* vp = v + (size_t)(kb * BLK) * ROWSTRIDE + h * DIMD;

        #pragma unroll
        for (int i = 0; i < 4; ++i) {
            float4 kv = *(const float4*)(kp + (size_t)(i * 32 + krow) * ROWSTRIDE + kcol);
            short4 ks;
            ks.x = f2bf(kv.x); ks.y = f2bf(kv.y); ks.z = f2bf(kv.z); ks.w = f2bf(kv.w);
            *(short4*)&Ksh[(i * 32 + krow) * K_LDF + kcol] = ks;

            const float* vr = vp + (size_t)(i * 32 + vkg * 4) * ROWSTRIDE + vd;
            short4 vs;
            vs.x = f2bf(vr[0 * ROWSTRIDE]);
            vs.y = f2bf(vr[1 * ROWSTRIDE]);
            vs.z = f2bf(vr[2 * ROWSTRIDE]);
            vs.w = f2bf(vr[3 * ROWSTRIDE]);
            *(short4*)&Vsh[vd * V_LD + i * 32 + vkg * 4] = vs;
        }
        __syncthreads();

        f32x4 s[8];
        #pragma unroll
        for (int n = 0; n < 8; ++n) {
            f32x4 z = {};
            #pragma unroll
            for (int kc = 0; kc < 2; ++kc) {
                bf16x8 kf = *(const bf16x8*)&Ksh[(n * 16 + lc) * K_LDF + kc * 32 + lr * 8];
                z = __builtin_amdgcn_mfma_f32_16x16x32_bf16(qf[kc], kf, z, 0, 0, 0);
            }
            s[n] = z * SCALE;
        }

        #pragma unroll
        for (int rr = 0; rr < 4; ++rr) {
            float mx = s[0][rr];
            #pragma unroll
            for (int n = 1; n < 8; ++n) mx = fmaxf(mx, s[n][rr]);
            #pragma unroll
            for (int off = 1; off < 16; off <<= 1)
                mx = fmaxf(mx, __shfl_xor(mx, off, 64));
            float mnew = fmaxf(m_run[rr], mx);
            float al = exp2f((m_run[rr] - mnew) * L2E);
            m_run[rr] = mnew;
            float sum = 0.0f;
            #pragma unroll
            for (int n = 0; n < 8; ++n) {
                float p = exp2f((s[n][rr] - mnew) * L2E);
                s[n][rr] = p;
                sum += p;
            }
            #pragma unroll
            for (int off = 1; off < 16; off <<= 1)
                sum += __shfl_xor(sum, off, 64);
            l_run[rr] = l_run[rr] * al + sum;
            #pragma unroll
            for (int dn = 0; dn < 4; ++dn) acc[dn][rr] *= al;
        }

        short* pw = &Psh[w][0];
        #pragma unroll
        for (int n = 0; n < 8; ++n) {
            #pragma unroll
            for (int rr = 0; rr < 4; ++rr) {
                pw[(lr * 4 + rr) * P_LD + n * 16 + lc] = f2bf(s[n][rr]);
            }
        }

        #pragma unroll
        for (int dn = 0; dn < 4; ++dn) {
            f32x4 o = acc[dn];
            #pragma unroll
            for (int kc = 0; kc < 4; ++kc) {
                bf16x8 pfr = *(const bf16x8*)&pw[lc * P_LD + kc * 32 + lr * 8];
                bf16x8 vf = *(const bf16x8*)&Vsh[(dn * 16 + lc) * V_LD + kc * 32 + lr * 8];
                o = __builtin_amdgcn_mfma_f32_16x16x32_bf16(pfr, vf, o, 0, 0, 0);
            }
            acc[dn] = o;
        }
    }

    float* op = out + (size_t)(r * BLK + w * 16) * ROWSTRIDE + h * DIMD;
    #pragma unroll
    for (int rr = 0; rr < 4; ++rr) {
        float inv = 1.0f / l_run[rr];
        float* orow = op + (size_t)(lr * 4 + rr) * ROWSTRIDE;
        #pragma unroll
        for (int dn = 0; dn < 4; ++dn) {
            orow[dn * 16 + lc] = acc[dn][rr] * inv;
        }
    }
}

extern "C" void kernel_launch(void* const* d_in, const int* in_sizes, int n_in,
                              void* d_out, int out_size, void* d_ws, size_t ws_size,
                              hipStream_t stream) {
    const float* q = (const float*)d_in[0];
    const float* k = (const float*)d_in[1];
    const float* v = (const float*)d_in[2];
    float* out = (float*)d_out;

    if (ws_size >= (size_t)WS_NEEDED) {
        short* Kb = (short*)d_ws;
        short* Vt = Kb + (size_t)NH * HEAD_ELEMS;
        prep_kernel<<<512, 256, 0, stream>>>(k, v, Kb, Vt);
        bsattn_main<<<512, 256, 0, stream>>>(q, Kb, Vt, out);
    } else {
        bsattn_fallback<<<dim3(NROW, NH), 512, 0, stream>>>(q, k, v, out);
    }
}